// Round 1
// baseline (5613.135 us; speedup 1.0000x reference)
//
#include <hip/hip_runtime.h>
#include <math.h>

#define NB 8192
#define H 1024
#define HH 512
#define NEXP 16

// ---------------- workspace layout (elements) ----------------
// top1:    int[8192]
// gval:    float[8192]
// counts:  int[16], offsets: int[16], bpos: int[16]
// scale:   float[8192]
// brows:   int[8192]
// total ~131 KB

__global__ __launch_bounds__(256) void zero_kernel(int* counts) {
    if (threadIdx.x < NEXP) counts[threadIdx.x] = 0;
}

// Gating: per 32-row tile, compute x1 = relu(q @ cls1_w^T + b1) into LDS,
// then logits = x1 @ cls3_w^T + b3, argmax + softmax gate value.
__global__ __launch_bounds__(256) void gating_kernel(
    const float* __restrict__ q,
    const float* __restrict__ w1, const float* __restrict__ b1,
    const float* __restrict__ w3, const float* __restrict__ b3,
    int* __restrict__ top1, float* __restrict__ gval, int* __restrict__ counts)
{
    __shared__ float qs[32][33];
    __shared__ float wsS[64][33];
    __shared__ float x1s[32][HH + 4];
    __shared__ float w3s[NEXP][HH];
    __shared__ float lg[32][NEXP];

    const int t = threadIdx.x;
    const int row0 = blockIdx.x * 32;
    const int tx = t & 31;   // col within chunk (cols tx and tx+32)
    const int ty = t >> 5;   // 0..7, owns rows ty*4 .. ty*4+3

    // stage cls3_w once
    for (int idx = t; idx < NEXP * HH; idx += 256)
        w3s[idx >> 9][idx & 511] = w3[idx];

    for (int c0 = 0; c0 < HH; c0 += 64) {
        float acc[4][2] = {};
        for (int kk = 0; kk < H; kk += 32) {
            __syncthreads();
            #pragma unroll
            for (int j = 0; j < 4; ++j) {
                int idx = t + j * 256; int r = idx >> 5, k = idx & 31;
                qs[r][k] = q[(size_t)(row0 + r) * H + kk + k];
            }
            #pragma unroll
            for (int j = 0; j < 8; ++j) {
                int idx = t + j * 256; int c = idx >> 5, k = idx & 31;
                wsS[c][k] = w1[(size_t)(c0 + c) * H + kk + k];
            }
            __syncthreads();
            #pragma unroll
            for (int k = 0; k < 32; ++k) {
                float wv0 = wsS[tx][k], wv1 = wsS[tx + 32][k];
                #pragma unroll
                for (int j = 0; j < 4; ++j) {
                    float qv = qs[ty * 4 + j][k];
                    acc[j][0] += qv * wv0;
                    acc[j][1] += qv * wv1;
                }
            }
        }
        float bias0 = b1[c0 + tx], bias1 = b1[c0 + tx + 32];
        #pragma unroll
        for (int j = 0; j < 4; ++j) {
            x1s[ty * 4 + j][c0 + tx]      = fmaxf(acc[j][0] + bias0, 0.f);
            x1s[ty * 4 + j][c0 + tx + 32] = fmaxf(acc[j][1] + bias1, 0.f);
        }
    }
    __syncthreads();

    // logits: thread t handles (m = t&15), rows (t>>4) and (t>>4)+16
    {
        int m = t & 15; int r2 = t >> 4;
        for (int rr = r2; rr < 32; rr += 16) {
            float s = b3[m];
            for (int j = 0; j < HH; ++j) s += x1s[rr][j] * w3s[m][j];
            lg[rr][m] = s;
        }
    }
    __syncthreads();

    if (t < 32) {
        float best = lg[t][0]; int bi = 0;
        #pragma unroll
        for (int m2 = 1; m2 < NEXP; ++m2) {
            float v = lg[t][m2];
            if (v > best) { best = v; bi = m2; }   // first-max tie-break, matches np.argmax
        }
        float se = 0.f;
        #pragma unroll
        for (int m2 = 0; m2 < NEXP; ++m2) se += expf(lg[t][m2] - best);
        int grow = row0 + t;
        top1[grow] = bi;
        gval[grow] = 1.f / se;   // softmax prob of the argmax (only positivity matters)
        atomicAdd(&counts[bi], 1);
    }
}

__global__ __launch_bounds__(64) void offsets_kernel(
    const int* __restrict__ counts, int* __restrict__ offsets, int* __restrict__ bpos)
{
    if (threadIdx.x == 0) {
        int run = 0;
        for (int e = 0; e < NEXP; ++e) { offsets[e] = run; bpos[e] = run; run += counts[e]; }
    }
}

__global__ __launch_bounds__(256) void scatter_kernel(
    const int* __restrict__ top1, int* __restrict__ bpos, int* __restrict__ brows)
{
    int b = blockIdx.x * 256 + threadIdx.x;
    int e = top1[b];
    int pos = atomicAdd(&bpos[e], 1);
    brows[pos] = b;
}

// Expert kernel: block = (tile of 32 rows, expert e).
// GEMM1: h[32][512] = relu(qrows @ w1[e]^T + b1[e])  (h kept in LDS)
// GEMM2: v[32][1024] = h @ w2[e]^T + b2[e]  -> written to vout (=d_out)
// per-row sum(v^2) -> scale[row] = g / max(g*||v||, 1e-6)
__global__ __launch_bounds__(256) void expert_kernel(
    const float* __restrict__ q,
    const float* __restrict__ ew1, const float* __restrict__ eb1,
    const float* __restrict__ ew2, const float* __restrict__ eb2,
    const int* __restrict__ counts, const int* __restrict__ offsets,
    const int* __restrict__ brows, const float* __restrict__ gval,
    float* __restrict__ vout, float* __restrict__ scale)
{
    const int e = blockIdx.y;
    const int cnt = counts[e];
    const int tile0 = blockIdx.x * 32;
    if (tile0 >= cnt) return;

    __shared__ int   rrow[32];
    __shared__ float rowsq[32];
    __shared__ float qs[32][33];
    __shared__ float wsS[64][33];
    __shared__ float hs[32][HH + 4];

    const int t = threadIdx.x;
    if (t < 32) {
        int idx = tile0 + t; if (idx >= cnt) idx = cnt - 1;  // tail: duplicate last row (benign)
        rrow[t] = brows[offsets[e] + idx];
        rowsq[t] = 0.f;
    }
    __syncthreads();

    const int tx = t & 31, ty = t >> 5;
    const float* w1 = ew1 + (size_t)e * HH * H;
    const float* w2 = ew2 + (size_t)e * H * HH;

    // ---- GEMM1 ----
    for (int c0 = 0; c0 < HH; c0 += 64) {
        float acc[4][2] = {};
        for (int kk = 0; kk < H; kk += 32) {
            __syncthreads();
            #pragma unroll
            for (int j = 0; j < 4; ++j) {
                int idx = t + j * 256; int r = idx >> 5, k = idx & 31;
                qs[r][k] = q[(size_t)rrow[r] * H + kk + k];
            }
            #pragma unroll
            for (int j = 0; j < 8; ++j) {
                int idx = t + j * 256; int c = idx >> 5, k = idx & 31;
                wsS[c][k] = w1[(size_t)(c0 + c) * H + kk + k];
            }
            __syncthreads();
            #pragma unroll
            for (int k = 0; k < 32; ++k) {
                float wv0 = wsS[tx][k], wv1 = wsS[tx + 32][k];
                #pragma unroll
                for (int j = 0; j < 4; ++j) {
                    float qv = qs[ty * 4 + j][k];
                    acc[j][0] += qv * wv0;
                    acc[j][1] += qv * wv1;
                }
            }
        }
        float bias0 = eb1[e * HH + c0 + tx], bias1 = eb1[e * HH + c0 + tx + 32];
        #pragma unroll
        for (int j = 0; j < 4; ++j) {
            hs[ty * 4 + j][c0 + tx]      = fmaxf(acc[j][0] + bias0, 0.f);
            hs[ty * 4 + j][c0 + tx + 32] = fmaxf(acc[j][1] + bias1, 0.f);
        }
    }
    __syncthreads();

    // ---- GEMM2 ----
    for (int c0 = 0; c0 < H; c0 += 64) {
        float acc[4][2] = {};
        for (int kk = 0; kk < HH; kk += 32) {
            __syncthreads();
            #pragma unroll
            for (int j = 0; j < 8; ++j) {
                int idx = t + j * 256; int c = idx >> 5, k = idx & 31;
                wsS[c][k] = w2[(size_t)(c0 + c) * HH + kk + k];
            }
            __syncthreads();
            #pragma unroll
            for (int k = 0; k < 32; ++k) {
                float wv0 = wsS[tx][k], wv1 = wsS[tx + 32][k];
                #pragma unroll
                for (int j = 0; j < 4; ++j) {
                    float hv = hs[ty * 4 + j][kk + k];
                    acc[j][0] += hv * wv0;
                    acc[j][1] += hv * wv1;
                }
            }
        }
        float bias0 = eb2[e * H + c0 + tx], bias1 = eb2[e * H + c0 + tx + 32];
        float ss[4];
        #pragma unroll
        for (int j = 0; j < 4; ++j) {
            float v0 = acc[j][0] + bias0, v1 = acc[j][1] + bias1;
            int r = ty * 4 + j;
            vout[(size_t)rrow[r] * H + c0 + tx]      = v0;
            vout[(size_t)rrow[r] * H + c0 + tx + 32] = v1;
            ss[j] = v0 * v0 + v1 * v1;
        }
        // reduce within the 32 threads sharing ty (a half-wave)
        #pragma unroll
        for (int j = 0; j < 4; ++j) {
            float s = ss[j];
            #pragma unroll
            for (int off = 16; off > 0; off >>= 1)
                s += __shfl_down(s, off, 32);
            if (tx == 0) rowsq[ty * 4 + j] += s;
        }
    }
    __syncthreads();

    if (t < 32) {
        int r = rrow[t];
        float n = sqrtf(rowsq[t]);
        float g = gval[r];
        scale[r] = g / fmaxf(g * n, 1e-6f);   // faithful to F.normalize(clamp) semantics
    }
}

// out = v * scale[row] + q   (float4, in-place on d_out)
__global__ __launch_bounds__(256) void finalize_kernel(
    float* __restrict__ out, const float* __restrict__ q, const float* __restrict__ scale)
{
    size_t i = (size_t)blockIdx.x * 256 + threadIdx.x;   // float4 index; H/4 = 256 per row
    float4 v = ((const float4*)out)[i];
    float4 qq = ((const float4*)q)[i];
    float s = scale[(int)(i >> 8)];
    float4 o;
    o.x = v.x * s + qq.x;
    o.y = v.y * s + qq.y;
    o.z = v.z * s + qq.z;
    o.w = v.w * s + qq.w;
    ((float4*)out)[i] = o;
}

extern "C" void kernel_launch(void* const* d_in, const int* in_sizes, int n_in,
                              void* d_out, int out_size, void* d_ws, size_t ws_size,
                              hipStream_t stream) {
    const float* q      = (const float*)d_in[0];
    const float* cls1_w = (const float*)d_in[1];
    const float* cls1_b = (const float*)d_in[2];
    const float* cls3_w = (const float*)d_in[3];
    const float* cls3_b = (const float*)d_in[4];
    const float* exp_w1 = (const float*)d_in[5];
    const float* exp_b1 = (const float*)d_in[6];
    const float* exp_w2 = (const float*)d_in[7];
    const float* exp_b2 = (const float*)d_in[8];
    float* out = (float*)d_out;

    int*   top1    = (int*)d_ws;
    float* gval    = (float*)d_ws + NB;
    int*   counts  = (int*)d_ws + 2 * NB;
    int*   offsets = counts + NEXP;
    int*   bpos    = offsets + NEXP;
    float* scale   = (float*)(bpos + NEXP);
    int*   brows   = (int*)(scale + NB);

    zero_kernel<<<1, 256, 0, stream>>>(counts);
    gating_kernel<<<NB / 32, 256, 0, stream>>>(q, cls1_w, cls1_b, cls3_w, cls3_b,
                                               top1, gval, counts);
    offsets_kernel<<<1, 64, 0, stream>>>(counts, offsets, bpos);
    scatter_kernel<<<NB / 256, 256, 0, stream>>>(top1, bpos, brows);
    expert_kernel<<<dim3(NB / 32, NEXP), 256, 0, stream>>>(
        q, exp_w1, exp_b1, exp_w2, exp_b2, counts, offsets, brows, gval, out, scale);
    finalize_kernel<<<(NB * H / 4) / 256, 256, 0, stream>>>(out, q, scale);
}

// Round 2
// 666.649 us; speedup vs baseline: 8.4199x; 8.4199x over previous
//
#include <hip/hip_runtime.h>
#include <math.h>

#define NB 8192
#define H 1024
#define HH 512
#define NEXP 16

// MFMA fragment types (16x16x32 bf16: 8 bf16 in = 4 VGPR, 4 f32 out)
typedef __attribute__((ext_vector_type(8))) short bfrag;
typedef __attribute__((ext_vector_type(4))) float f4;

__device__ __forceinline__ f4 MF(bfrag a, bfrag b, f4 c) {
    return __builtin_amdgcn_mfma_f32_16x16x32_bf16(a, b, c, 0, 0, 0);
}
__device__ __forceinline__ unsigned short f2bf(float f) {  // RNE fp32->bf16
    unsigned u = __float_as_uint(f);
    u += 0x7fff + ((u >> 16) & 1);
    return (unsigned short)(u >> 16);
}
__device__ __forceinline__ float bf2f(unsigned short h) {
    return __uint_as_float((unsigned)h << 16);
}

__global__ __launch_bounds__(64) void zero_kernel(int* counts, int* ambig_cnt) {
    if (threadIdx.x < NEXP) counts[threadIdx.x] = 0;
    if (threadIdx.x == 0) *ambig_cnt = 0;
}

// fp32 -> (bf16 hi, bf16 lo) split, 4 elem/thread
__global__ __launch_bounds__(256) void convert_split(
    const float* __restrict__ src, unsigned short* __restrict__ hi,
    unsigned short* __restrict__ lo, int n4)
{
    int i = blockIdx.x * 256 + threadIdx.x;
    if (i >= n4) return;
    float4 v = ((const float4*)src)[i];
    ushort4 h, l;
    h.x = f2bf(v.x); l.x = f2bf(v.x - bf2f(h.x));
    h.y = f2bf(v.y); l.y = f2bf(v.y - bf2f(h.y));
    h.z = f2bf(v.z); l.z = f2bf(v.z - bf2f(h.z));
    h.w = f2bf(v.w); l.w = f2bf(v.w - bf2f(h.w));
    ((ushort4*)hi)[i] = h;
    ((ushort4*)lo)[i] = l;
}

__global__ __launch_bounds__(256) void convert_plain(
    const float* __restrict__ src, unsigned short* __restrict__ dst, int n4)
{
    int i = blockIdx.x * 256 + threadIdx.x;
    if (i >= n4) return;
    float4 v = ((const float4*)src)[i];
    ushort4 h;
    h.x = f2bf(v.x); h.y = f2bf(v.y); h.z = f2bf(v.z); h.w = f2bf(v.w);
    ((ushort4*)dst)[i] = h;
}

// Gating: 32 rows/block. GEMM1 via split-bf16 3-term MFMA (err ~2e-5 on logits),
// relu'd x1 stored to LDS as hi/lo bf16, logits via 3-term MFMA, argmax + gap flag.
__global__ __launch_bounds__(256) void gating_kernel(
    const unsigned short* __restrict__ qhi, const unsigned short* __restrict__ qlo,
    const unsigned short* __restrict__ w1hi, const unsigned short* __restrict__ w1lo,
    const float* __restrict__ b1,
    const unsigned short* __restrict__ w3hi, const unsigned short* __restrict__ w3lo,
    const float* __restrict__ b3,
    int* __restrict__ top1, float* __restrict__ gval,
    int* __restrict__ ambig_rows, int* __restrict__ ambig_cnt)
{
    __shared__ unsigned short xhi[32][HH + 8];
    __shared__ unsigned short xlo[32][HH + 8];
    __shared__ float lgp[4][32][NEXP];

    const int t = threadIdx.x;
    const int wave = t >> 6, lane = t & 63, quad = lane >> 4, l16 = lane & 15;
    const int row0 = blockIdx.x * 32;

    const f4 z4 = {0.f, 0.f, 0.f, 0.f};
    f4 acc[2][8];
    #pragma unroll
    for (int rb = 0; rb < 2; ++rb)
        #pragma unroll
        for (int cb = 0; cb < 8; ++cb) acc[rb][cb] = z4;

    const size_t ar0 = (size_t)(row0 + l16) * H + quad * 8;
    const size_t ar1 = (size_t)(row0 + 16 + l16) * H + quad * 8;
    for (int kk = 0; kk < H; kk += 32) {
        bfrag a0h = *(const bfrag*)(qhi + ar0 + kk);
        bfrag a0l = *(const bfrag*)(qlo + ar0 + kk);
        bfrag a1h = *(const bfrag*)(qhi + ar1 + kk);
        bfrag a1l = *(const bfrag*)(qlo + ar1 + kk);
        #pragma unroll
        for (int cb = 0; cb < 8; ++cb) {
            size_t boff = (size_t)(wave * 128 + cb * 16 + l16) * H + kk + quad * 8;
            bfrag bh = *(const bfrag*)(w1hi + boff);
            bfrag bl = *(const bfrag*)(w1lo + boff);
            acc[0][cb] = MF(a0h, bh, acc[0][cb]);
            acc[0][cb] = MF(a0h, bl, acc[0][cb]);
            acc[0][cb] = MF(a0l, bh, acc[0][cb]);
            acc[1][cb] = MF(a1h, bh, acc[1][cb]);
            acc[1][cb] = MF(a1h, bl, acc[1][cb]);
            acc[1][cb] = MF(a1l, bh, acc[1][cb]);
        }
    }
    // epilogue: +bias, relu, split to LDS (C layout: col=lane&15, row=quad*4+reg)
    #pragma unroll
    for (int cb = 0; cb < 8; ++cb) {
        int col = wave * 128 + cb * 16 + l16;
        float bias = b1[col];
        #pragma unroll
        for (int rb = 0; rb < 2; ++rb)
            #pragma unroll
            for (int i = 0; i < 4; ++i) {
                int r = rb * 16 + quad * 4 + i;
                float v = fmaxf(acc[rb][cb][i] + bias, 0.f);
                unsigned short hh = f2bf(v);
                xhi[r][col] = hh;
                xlo[r][col] = f2bf(v - bf2f(hh));
            }
    }
    __syncthreads();

    // logits: wave handles k-steps [wave*4, wave*4+4) of 16
    f4 lacc0 = z4, lacc1 = z4;
    #pragma unroll
    for (int ks = 0; ks < 4; ++ks) {
        int kk = (wave * 4 + ks) * 32 + quad * 8;
        bfrag ah0 = *(const bfrag*)&xhi[l16][kk];
        bfrag al0 = *(const bfrag*)&xlo[l16][kk];
        bfrag ah1 = *(const bfrag*)&xhi[16 + l16][kk];
        bfrag al1 = *(const bfrag*)&xlo[16 + l16][kk];
        size_t boff = (size_t)l16 * HH + kk;
        bfrag bh = *(const bfrag*)(w3hi + boff);
        bfrag bl = *(const bfrag*)(w3lo + boff);
        lacc0 = MF(ah0, bh, lacc0); lacc0 = MF(ah0, bl, lacc0); lacc0 = MF(al0, bh, lacc0);
        lacc1 = MF(ah1, bh, lacc1); lacc1 = MF(ah1, bl, lacc1); lacc1 = MF(al1, bh, lacc1);
    }
    #pragma unroll
    for (int i = 0; i < 4; ++i) {
        lgp[wave][quad * 4 + i][l16] = lacc0[i];
        lgp[wave][16 + quad * 4 + i][l16] = lacc1[i];
    }
    __syncthreads();

    if (t < 32) {
        float lg[NEXP];
        #pragma unroll
        for (int m = 0; m < NEXP; ++m)
            lg[m] = lgp[0][t][m] + lgp[1][t][m] + lgp[2][t][m] + lgp[3][t][m] + b3[m];
        float best = lg[0], second = -3.4e38f; int bi = 0;
        #pragma unroll
        for (int m = 1; m < NEXP; ++m) {
            float v = lg[m];
            if (v > best) { second = best; best = v; bi = m; }
            else if (v > second) second = v;
        }
        float se = 0.f;
        #pragma unroll
        for (int m = 0; m < NEXP; ++m) se += expf(lg[m] - best);
        int grow = row0 + t;
        top1[grow] = bi;
        gval[grow] = 1.f / se;
        if (best - second < 1e-3f) {             // ambiguous under ~2e-5 bf16-split error
            int pos = atomicAdd(ambig_cnt, 1);
            if (pos < NB) ambig_rows[pos] = grow;
        }
    }
}

// Exact-fp32 recompute of gating for ambiguous rows (expected ~25 rows).
__global__ __launch_bounds__(256) void fixup_kernel(
    const float* __restrict__ q, const float* __restrict__ w1, const float* __restrict__ b1,
    const float* __restrict__ w3, const float* __restrict__ b3,
    const int* __restrict__ ambig_rows, const int* __restrict__ ambig_cnt,
    int* __restrict__ top1, float* __restrict__ gval)
{
    __shared__ float qrow[H];
    __shared__ float x1[HH];
    __shared__ float lg[NEXP];
    const int t = threadIdx.x;
    int nn = *ambig_cnt; if (nn > NB) nn = NB;
    for (int ii = blockIdx.x; ii < nn; ii += 64) {
        int row = ambig_rows[ii];
        for (int j = t; j < H; j += 256) qrow[j] = q[(size_t)row * H + j];
        __syncthreads();
        for (int c = t; c < HH; c += 256) {
            const float4* wv = (const float4*)(w1 + (size_t)c * H);
            const float4* qv = (const float4*)qrow;
            float s = 0.f;
            for (int k = 0; k < H / 4; ++k) {
                float4 a = qv[k], b = wv[k];
                s += a.x * b.x + a.y * b.y + a.z * b.z + a.w * b.w;
            }
            x1[c] = fmaxf(s + b1[c], 0.f);
        }
        __syncthreads();
        if (t < NEXP) {
            float s = 0.f;
            const float* wr = w3 + (size_t)t * HH;
            for (int k = 0; k < HH; ++k) s += x1[k] * wr[k];
            lg[t] = s + b3[t];
        }
        __syncthreads();
        if (t == 0) {
            float best = lg[0]; int bi = 0;
            for (int m = 1; m < NEXP; ++m) if (lg[m] > best) { best = lg[m]; bi = m; }
            float se = 0.f;
            for (int m = 0; m < NEXP; ++m) se += expf(lg[m] - best);
            top1[row] = bi;
            gval[row] = 1.f / se;
        }
        __syncthreads();
    }
}

__global__ __launch_bounds__(256) void count_kernel(
    const int* __restrict__ top1, int* __restrict__ counts)
{
    int b = blockIdx.x * 256 + threadIdx.x;
    atomicAdd(&counts[top1[b]], 1);
}

__global__ __launch_bounds__(64) void offsets_kernel(
    const int* __restrict__ counts, int* __restrict__ offsets, int* __restrict__ bpos)
{
    if (threadIdx.x == 0) {
        int run = 0;
        for (int e = 0; e < NEXP; ++e) { offsets[e] = run; bpos[e] = run; run += counts[e]; }
    }
}

__global__ __launch_bounds__(256) void scatter_kernel(
    const int* __restrict__ top1, int* __restrict__ bpos, int* __restrict__ brows)
{
    int b = blockIdx.x * 256 + threadIdx.x;
    int e = top1[b];
    int pos = atomicAdd(&bpos[e], 1);
    brows[pos] = b;
}

// Expert: 32 rows/block, 4 waves. bf16 MFMA, fragments loaded directly from
// global k-major bf16 (no LDS staging in K-loop); h round-trips LDS.
// Finalize (1/||v|| * v + q) fused in the epilogue.
__global__ __launch_bounds__(256, 1) void expert_kernel(
    const float* __restrict__ qf, const unsigned short* __restrict__ qb,
    const unsigned short* __restrict__ ew1b, const float* __restrict__ eb1,
    const unsigned short* __restrict__ ew2b, const float* __restrict__ eb2,
    const int* __restrict__ counts, const int* __restrict__ offsets,
    const int* __restrict__ brows, const float* __restrict__ gval,
    float* __restrict__ out)
{
    const int e = blockIdx.y;
    const int cnt = counts[e];
    const int tile0 = blockIdx.x * 32;
    if (tile0 >= cnt) return;

    __shared__ int rrow[32];
    __shared__ unsigned short hs[32][HH + 8];
    __shared__ float rqp[4][32];
    __shared__ float sscale[32];

    const int t = threadIdx.x;
    const int wave = t >> 6, lane = t & 63, quad = lane >> 4, l16 = lane & 15;

    if (t < 32) {
        int idx = tile0 + t; if (idx >= cnt) idx = cnt - 1;  // tail dup: benign
        rrow[t] = brows[offsets[e] + idx];
    }
    __syncthreads();

    const unsigned short* w1p = ew1b + (size_t)e * HH * H;
    const unsigned short* w2p = ew2b + (size_t)e * H * HH;
    const f4 z4 = {0.f, 0.f, 0.f, 0.f};

    // ---- GEMM1: h[32][512] ----
    f4 acc1[2][8];
    #pragma unroll
    for (int rb = 0; rb < 2; ++rb)
        #pragma unroll
        for (int cb = 0; cb < 8; ++cb) acc1[rb][cb] = z4;

    const size_t ar0 = (size_t)rrow[l16] * H + quad * 8;
    const size_t ar1 = (size_t)rrow[16 + l16] * H + quad * 8;
    for (int kk = 0; kk < H; kk += 32) {
        bfrag a0 = *(const bfrag*)(qb + ar0 + kk);
        bfrag a1 = *(const bfrag*)(qb + ar1 + kk);
        #pragma unroll
        for (int cb = 0; cb < 8; ++cb) {
            bfrag b = *(const bfrag*)(w1p + (size_t)(wave * 128 + cb * 16 + l16) * H + kk + quad * 8);
            acc1[0][cb] = MF(a0, b, acc1[0][cb]);
            acc1[1][cb] = MF(a1, b, acc1[1][cb]);
        }
    }
    #pragma unroll
    for (int cb = 0; cb < 8; ++cb) {
        int col = wave * 128 + cb * 16 + l16;
        float bias = eb1[e * HH + col];
        #pragma unroll
        for (int rb = 0; rb < 2; ++rb)
            #pragma unroll
            for (int i = 0; i < 4; ++i)
                hs[rb * 16 + quad * 4 + i][col] = f2bf(fmaxf(acc1[rb][cb][i] + bias, 0.f));
    }
    __syncthreads();

    // ---- GEMM2: v[32][1024], wave owns cols [wave*256, +256) ----
    f4 acc2[2][16];
    #pragma unroll
    for (int rb = 0; rb < 2; ++rb)
        #pragma unroll
        for (int cb = 0; cb < 16; ++cb) acc2[rb][cb] = z4;

    for (int kk = 0; kk < HH; kk += 32) {
        bfrag a0 = *(const bfrag*)&hs[l16][kk + quad * 8];
        bfrag a1 = *(const bfrag*)&hs[16 + l16][kk + quad * 8];
        #pragma unroll
        for (int cb = 0; cb < 16; ++cb) {
            bfrag b = *(const bfrag*)(w2p + (size_t)(wave * 256 + cb * 16 + l16) * HH + kk + quad * 8);
            acc2[0][cb] = MF(a0, b, acc2[0][cb]);
            acc2[1][cb] = MF(a1, b, acc2[1][cb]);
        }
    }

    // bias + per-row sum(v^2)
    float rs0[4] = {0.f, 0.f, 0.f, 0.f}, rs1[4] = {0.f, 0.f, 0.f, 0.f};
    #pragma unroll
    for (int cb = 0; cb < 16; ++cb) {
        int col = wave * 256 + cb * 16 + l16;
        float bias = eb2[e * H + col];
        #pragma unroll
        for (int i = 0; i < 4; ++i) {
            float v0 = acc2[0][cb][i] + bias; acc2[0][cb][i] = v0; rs0[i] += v0 * v0;
            float v1 = acc2[1][cb][i] + bias; acc2[1][cb][i] = v1; rs1[i] += v1 * v1;
        }
    }
    #pragma unroll
    for (int i = 0; i < 4; ++i) {
        float s0 = rs0[i], s1 = rs1[i];
        #pragma unroll
        for (int off = 8; off; off >>= 1) {
            s0 += __shfl_xor(s0, off, 16);
            s1 += __shfl_xor(s1, off, 16);
        }
        if (l16 == 0) {
            rqp[wave][quad * 4 + i] = s0;
            rqp[wave][16 + quad * 4 + i] = s1;
        }
    }
    __syncthreads();
    if (t < 32) {
        float n = sqrtf(rqp[0][t] + rqp[1][t] + rqp[2][t] + rqp[3][t]);
        float g = gval[rrow[t]];
        sscale[t] = g / fmaxf(g * n, 1e-6f);   // == 1/n unless degenerate
    }
    __syncthreads();

    // fused finalize: out = v*scale + q
    #pragma unroll
    for (int rb = 0; rb < 2; ++rb)
        #pragma unroll
        for (int i = 0; i < 4; ++i) {
            int r = rb * 16 + quad * 4 + i;
            int gr = rrow[r];
            float sc = sscale[r];
            size_t base = (size_t)gr * H + wave * 256 + l16;
            #pragma unroll
            for (int cb = 0; cb < 16; ++cb) {
                size_t idx = base + cb * 16;
                out[idx] = acc2[rb][cb][i] * sc + qf[idx];
            }
        }
}

extern "C" void kernel_launch(void* const* d_in, const int* in_sizes, int n_in,
                              void* d_out, int out_size, void* d_ws, size_t ws_size,
                              hipStream_t stream) {
    const float* q      = (const float*)d_in[0];
    const float* cls1_w = (const float*)d_in[1];
    const float* cls1_b = (const float*)d_in[2];
    const float* cls3_w = (const float*)d_in[3];
    const float* cls3_b = (const float*)d_in[4];
    const float* exp_w1 = (const float*)d_in[5];
    const float* exp_b1 = (const float*)d_in[6];
    const float* exp_w2 = (const float*)d_in[7];
    const float* exp_b2 = (const float*)d_in[8];
    float* out = (float*)d_out;

    // workspace layout (~66.2 MB; assumes ws_size covers it)
    unsigned short* qhi   = (unsigned short*)d_ws;
    unsigned short* qlo   = qhi + (size_t)NB * H;
    unsigned short* w1chi = qlo + (size_t)NB * H;
    unsigned short* w1clo = w1chi + HH * H;
    unsigned short* w3chi = w1clo + HH * H;
    unsigned short* w3clo = w3chi + NEXP * HH;
    unsigned short* ew1b  = w3clo + NEXP * HH;
    unsigned short* ew2b  = ew1b + (size_t)NEXP * HH * H;
    int*   top1      = (int*)(ew2b + (size_t)NEXP * H * HH);
    float* gvalp     = (float*)(top1 + NB);
    int*   counts    = (int*)(gvalp + NB);
    int*   offsets   = counts + NEXP;
    int*   bpos      = offsets + NEXP;
    int*   brows     = bpos + NEXP;
    int*   ambig_rows = brows + NB;
    int*   ambig_cnt  = ambig_rows + NB;

    zero_kernel<<<1, 64, 0, stream>>>(counts, ambig_cnt);
    convert_split<<<(NB * H / 4 + 255) / 256, 256, 0, stream>>>(q, qhi, qlo, NB * H / 4);
    convert_split<<<(HH * H / 4 + 255) / 256, 256, 0, stream>>>(cls1_w, w1chi, w1clo, HH * H / 4);
    convert_split<<<(NEXP * HH / 4 + 255) / 256, 256, 0, stream>>>(cls3_w, w3chi, w3clo, NEXP * HH / 4);
    convert_plain<<<(NEXP * HH * H / 4 + 255) / 256, 256, 0, stream>>>(exp_w1, ew1b, NEXP * HH * H / 4);
    convert_plain<<<(NEXP * H * HH / 4 + 255) / 256, 256, 0, stream>>>(exp_w2, ew2b, NEXP * H * HH / 4);
    gating_kernel<<<NB / 32, 256, 0, stream>>>(qhi, qlo, w1chi, w1clo, cls1_b,
                                               w3chi, w3clo, cls3_b,
                                               top1, gvalp, ambig_rows, ambig_cnt);
    fixup_kernel<<<64, 256, 0, stream>>>(q, cls1_w, cls1_b, cls3_w, cls3_b,
                                         ambig_rows, ambig_cnt, top1, gvalp);
    count_kernel<<<NB / 256, 256, 0, stream>>>(top1, counts);
    offsets_kernel<<<1, 64, 0, stream>>>(counts, offsets, bpos);
    scatter_kernel<<<NB / 256, 256, 0, stream>>>(top1, bpos, brows);
    expert_kernel<<<dim3(NB / 32, NEXP), 256, 0, stream>>>(
        q, qhi, ew1b, exp_b1, ew2b, exp_b2, counts, offsets, brows, gvalp, out);
}